// Round 9
// baseline (99.152 us; speedup 1.0000x reference)
//
#include <hip/hip_runtime.h>
#include <math.h>

#define VOCAB 100000
#define BATCH 4096
#define DOC_LEN 200
#define EMBED_DIM 300
#define NUM_CLASSES 20

// ---------------------------------------------------------------------------
// Kernel 1:  P[v][c] = sum_k emb[v][k] * (W[c][k]/DOC_LEN)
// r8's compute core (K-split 5 waves x R=2, W broadcast from LDS, [s][c][r]
// partials) + COALESCED emb staging through LDS.
// r8 post-mortem: halving LDS work didn't move time; ~80us is invariant
// across occupancy 3..30 waves/CU. Diagnosis: lane-per-row global reads
// (16B/lane, 1200B stride) = 64 lines per wave-load, 7.5M 16B L2-miss
// requests, MSHR-throttled. Fix: stage [128][60] chunk tiles via
// global_load_lds with sequential 48B-segment addresses (~2M line-granular
// requests), consume from LDS at floor throughput.
// ---------------------------------------------------------------------------
#define K1_BLOCK 320
#define K1_RPB   128                                   // rows per block
#define K1_GRID  ((VOCAB + K1_RPB - 1) / K1_RPB)       // 782
#define SW_FLOATS (NUM_CLASSES * EMBED_DIM)            // 6000
#define TILE_SLOTS (K1_RPB * 15)                       // 1920 x 16B

// one k-value: 5 uniform W-quad reads, 8 FMAs each (4 classes x 2 rows)
#define FMA2_K(av, bv, kw)                                                \
    {                                                                     \
        _Pragma("unroll")                                                 \
        for (int c4 = 0; c4 < NUM_CLASSES; c4 += 4) {                     \
            const float4 w =                                              \
                *reinterpret_cast<const float4*>(&sWT[(kw)][c4]);         \
            acc0[c4 + 0] += (av) * w.x;  acc1[c4 + 0] += (bv) * w.x;      \
            acc0[c4 + 1] += (av) * w.y;  acc1[c4 + 1] += (bv) * w.y;      \
            acc0[c4 + 2] += (av) * w.z;  acc1[c4 + 2] += (bv) * w.z;      \
            acc0[c4 + 3] += (av) * w.w;  acc1[c4 + 3] += (bv) * w.w;      \
        }                                                                 \
    }

__device__ inline void load_lds16(const float* g, float* l) {
    __builtin_amdgcn_global_load_lds(
        (const __attribute__((address_space(1))) void*)g,
        (__attribute__((address_space(3))) void*)l, 16, 0, 0);
}

__global__ __launch_bounds__(K1_BLOCK) void project_kernel(
    const float* __restrict__ emb,   // (VOCAB, 300)
    const float* __restrict__ W,     // (20, 300)
    float*       __restrict__ P)     // (VOCAB, 20)  [workspace]
{
    // layout: [0..5999] sWT; [6000..] union of tile (7680 f) / sPart (12800 f)
    __shared__ __align__(16) float smem[SW_FLOATS + 5 * NUM_CLASSES * K1_RPB];
    float (*sWT)[NUM_CLASSES] = reinterpret_cast<float (*)[NUM_CLASSES]>(smem);
    float*  tileF  = smem + SW_FLOATS;                 // 16B-aligned (24000B)
    float4* tileF4 = reinterpret_cast<float4*>(tileF);

    const int tid = threadIdx.x;
    const float inv = 1.0f / (float)DOC_LEN;
    for (int i = tid; i < SW_FLOATS; i += K1_BLOCK) {
        const int c = i / EMBED_DIM;
        const int k = i - c * EMBED_DIM;
        sWT[k][c] = W[i] * inv;                        // fold mean into W
    }

    const int s     = tid >> 6;                        // k-slice = wave, 0..4
    const int lane  = tid & 63;
    const int rbase = blockIdx.x * K1_RPB;

    float acc0[NUM_CLASSES], acc1[NUM_CLASSES];
    #pragma unroll
    for (int c = 0; c < NUM_CLASSES; ++c) { acc0[c] = 0.0f; acc1[c] = 0.0f; }

    for (int j = 0; j < 5; ++j) {                      // 5 K-chunks of 60
        __syncthreads();                               // prev compute done (j=0: W done)

        // ---- stage tile[128 rows][60 cols of chunk j]: 1920 16B slots ----
        // slot -> (row, q); q = s2*3+t covers floats k = s2*60 + j*12 + t*4 ..
        #pragma unroll
        for (int rnd = 0; rnd < 6; ++rnd) {
            const int slot = rnd * K1_BLOCK + tid;
            const int row  = slot / 15;
            const int q    = slot - row * 15;
            const int s2   = q / 3;
            const int t    = q - s2 * 3;
            int grow = rbase + row;
            if (grow >= VOCAB) grow = VOCAB - 1;       // clamp reads only
            const float* g = emb + (size_t)grow * EMBED_DIM
                           + (size_t)(s2 * 60 + j * 12 + t * 4);
            // wave-uniform LDS base; HW adds lane*16
            const int lofs =
                __builtin_amdgcn_readfirstlane((rnd * K1_BLOCK + (tid & ~63)) * 4);
            load_lds16(g, tileF + lofs);
        }
        __syncthreads();                               // vmcnt(0) drained by barrier

        // ---- compute chunk j: wave s consumes its 12 k-values ----
        #pragma unroll
        for (int qq = 0; qq < 3; ++qq) {
            const float4 a = tileF4[lane * 15 + s * 3 + qq];        // row lane
            const float4 b = tileF4[(lane + 64) * 15 + s * 3 + qq]; // row lane+64
            const int kb = s * 60 + j * 12 + qq * 4;
            FMA2_K(a.x, b.x, kb + 0)  FMA2_K(a.y, b.y, kb + 1)
            FMA2_K(a.z, b.z, kb + 2)  FMA2_K(a.w, b.w, kb + 3)
        }
    }
    __syncthreads();                                   // all compute done

    // ---- partials [s][c][r] over the tile region (conflict-free) ----
    float* sP = tileF;
    #pragma unroll
    for (int c = 0; c < NUM_CLASSES; ++c) {
        sP[(s * NUM_CLASSES + c) * K1_RPB + lane]      = acc0[c];
        sP[(s * NUM_CLASSES + c) * K1_RPB + lane + 64] = acc1[c];
    }
    __syncthreads();

    // reduce 5 slices: 2560 outputs, 8/thread; c-major -> stride-1 reads
    #pragma unroll
    for (int jj = 0; jj < 8; ++jj) {
        const int oi = tid + jj * K1_BLOCK;            // 0..2559
        const int r  = oi & (K1_RPB - 1);
        const int c  = oi >> 7;
        float v = sP[(0 * NUM_CLASSES + c) * K1_RPB + r]
                + sP[(1 * NUM_CLASSES + c) * K1_RPB + r]
                + sP[(2 * NUM_CLASSES + c) * K1_RPB + r]
                + sP[(3 * NUM_CLASSES + c) * K1_RPB + r]
                + sP[(4 * NUM_CLASSES + c) * K1_RPB + r];
        const int gr = rbase + r;
        if (gr < VOCAB)
            P[(size_t)gr * NUM_CLASSES + c] = v;
    }
}

// ---------------------------------------------------------------------------
// Kernel 2: out[doc] = softmax( sum_l P[x[doc][l]] + b )   (unchanged)
// ---------------------------------------------------------------------------
#define K2_BLOCK 256
#define DOCS_PER_BLOCK 4

__global__ __launch_bounds__(K2_BLOCK) void pool_softmax_kernel(
    const float* __restrict__ P,     // (VOCAB, 20), pre-scaled by 1/DOC_LEN
    const float* __restrict__ bias,  // (20,)
    const int*   __restrict__ x,     // (BATCH, 200)
    float*       __restrict__ out)   // (BATCH, 20)
{
    __shared__ int sidx[DOCS_PER_BLOCK][DOC_LEN];

    const int doc0 = blockIdx.x * DOCS_PER_BLOCK;
    const int tid  = threadIdx.x;

    for (int i = tid; i < DOCS_PER_BLOCK * DOC_LEN; i += K2_BLOCK)
        (&sidx[0][0])[i] = x[doc0 * DOC_LEN + i];
    __syncthreads();

    const int wave = tid >> 6;
    const int lane = tid & 63;
    const int doc  = doc0 + wave;
    const int g    = lane / NUM_CLASSES;          // 0..2 active, 3 idle
    const int c    = lane - g * NUM_CLASSES;

    float acc = 0.0f;
    if (g < 3) {
        #pragma unroll 4
        for (int l = g; l < DOC_LEN; l += 3) {
            const int row = sidx[wave][l];        // LDS broadcast per group
            acc += P[(size_t)row * NUM_CLASSES + c];
        }
    }

    const float a1 = __shfl(acc, lane + 20, 64);
    const float a2 = __shfl(acc, lane + 40, 64);

    float v = (lane < NUM_CLASSES) ? (acc + a1 + a2 + bias[c]) : -INFINITY;

    float m = v;
    #pragma unroll
    for (int off = 16; off > 0; off >>= 1)
        m = fmaxf(m, __shfl_xor(m, off, 32));
    const float e = (lane < NUM_CLASSES) ? expf(v - m) : 0.0f;
    float s = e;
    #pragma unroll
    for (int off = 16; off > 0; off >>= 1)
        s += __shfl_xor(s, off, 32);

    if (lane < NUM_CLASSES)
        out[doc * NUM_CLASSES + lane] = e / s;
}

extern "C" void kernel_launch(void* const* d_in, const int* in_sizes, int n_in,
                              void* d_out, int out_size, void* d_ws, size_t ws_size,
                              hipStream_t stream) {
    const float* emb  = (const float*)d_in[0];
    const float* W    = (const float*)d_in[1];
    const float* bias = (const float*)d_in[2];
    const int*   x    = (const int*)d_in[3];
    float* out = (float*)d_out;
    float* P   = (float*)d_ws;   // needs VOCAB*20*4 = 8,000,000 B

    project_kernel<<<K1_GRID, K1_BLOCK, 0, stream>>>(emb, W, P);
    pool_softmax_kernel<<<BATCH / DOCS_PER_BLOCK, K2_BLOCK, 0, stream>>>(P, bias, x, out);
}